// Round 1
// baseline (2031.618 us; speedup 1.0000x reference)
//
#include <hip/hip_runtime.h>
#include <hip/hip_bf16.h>

#define NN 100000
#define NE 1600000
#define INF_ 128
#define OC 128   // NHEAD*OUT_F
#define NH 4
#define ALPHA 0.2f

__device__ __forceinline__ unsigned encf(float f) {
    unsigned u = __float_as_uint(f);
    return (u & 0x80000000u) ? ~u : (u | 0x80000000u);
}
__device__ __forceinline__ float decf(unsigned u) {
    return (u & 0x80000000u) ? __uint_as_float(u & 0x7FFFFFFFu) : __uint_as_float(~u);
}
__device__ __forceinline__ float lrelu(float x) {
    return x > 0.0f ? x : ALPHA * x;
}

// GEMM h = x @ W, fused per-node attention halves al/ar.
// Block: 256 threads, 32 rows per block. W (64KB) + x rows (16KB) in LDS.
__global__ __launch_bounds__(256) void k_gemm(
    const float* __restrict__ x, const float* __restrict__ W,
    const float* __restrict__ a_l, const float* __restrict__ a_r,
    float* __restrict__ h, float* __restrict__ al, float* __restrict__ ar) {
    __shared__ float Wl[INF_ * OC];      // 64 KB
    __shared__ float xs[32][INF_];       // 16 KB
    const int tid = threadIdx.x;
    for (int i = tid * 4; i < INF_ * OC; i += 256 * 4)
        *(float4*)&Wl[i] = *(const float4*)&W[i];
    const int rowBase = blockIdx.x * 32;
    for (int i = tid * 4; i < 32 * INF_; i += 256 * 4) {
        int r = i >> 7, k = i & 127;
        *(float4*)&xs[r][k] = *(const float4*)&x[(rowBase + r) * INF_ + k];
    }
    __syncthreads();

    const int col = tid & 127;
    const int grp = tid >> 7;          // 0/1: rows 0-15 vs 16-31
    const int hd  = col >> 5;
    const float alc = a_l[col], arc = a_r[col];

    for (int pass = 0; pass < 4; ++pass) {
        const int r0 = grp * 16 + pass * 4;
        float acc0 = 0.f, acc1 = 0.f, acc2 = 0.f, acc3 = 0.f;
#pragma unroll 8
        for (int k = 0; k < INF_; ++k) {
            float w = Wl[k * OC + col];
            acc0 += xs[r0 + 0][k] * w;
            acc1 += xs[r0 + 1][k] * w;
            acc2 += xs[r0 + 2][k] * w;
            acc3 += xs[r0 + 3][k] * w;
        }
        float accs[4] = {acc0, acc1, acc2, acc3};
#pragma unroll
        for (int i = 0; i < 4; ++i) {
            const int row = rowBase + r0 + i;
            float v = accs[i];
            h[row * OC + col] = v;
            float pl = v * alc;
            float pr = v * arc;
#pragma unroll
            for (int m = 1; m <= 16; m <<= 1) {
                pl += __shfl_xor(pl, m);
                pr += __shfl_xor(pr, m);
            }
            if ((col & 31) == 0) {
                al[row * NH + hd] = pl;
                ar[row * NH + hd] = pr;
            }
        }
    }
}

// Per-edge raw score + segment max (encoded-uint atomicMax).
__global__ __launch_bounds__(256) void k_edge_max(
    const int* __restrict__ row, const int* __restrict__ col,
    const float* __restrict__ al, const float* __restrict__ ar,
    float* __restrict__ e, unsigned* __restrict__ m_enc) {
    const int ed = blockIdx.x * 256 + threadIdx.x;
    if (ed >= NE) return;
    const int r = row[ed], c = col[ed];
    float4 a = *(const float4*)&al[r * NH];
    float4 b = *(const float4*)&ar[c * NH];
    float4 ev;
    ev.x = lrelu(a.x + b.x);
    ev.y = lrelu(a.y + b.y);
    ev.z = lrelu(a.z + b.z);
    ev.w = lrelu(a.w + b.w);
    *(float4*)&e[ed * NH] = ev;
    atomicMax(&m_enc[r * NH + 0], encf(ev.x));
    atomicMax(&m_enc[r * NH + 1], encf(ev.y));
    atomicMax(&m_enc[r * NH + 2], encf(ev.z));
    atomicMax(&m_enc[r * NH + 3], encf(ev.w));
}

// Per-edge exp(e - m[row]) + segment sum. p overwrites e in place.
__global__ __launch_bounds__(256) void k_exp_sum(
    const int* __restrict__ row, const unsigned* __restrict__ m_enc,
    float* __restrict__ ep, float* __restrict__ s) {
    const int ed = blockIdx.x * 256 + threadIdx.x;
    if (ed >= NE) return;
    const int r = row[ed];
    float4 ev = *(const float4*)&ep[ed * NH];
    float m0 = decf(m_enc[r * NH + 0]);
    float m1 = decf(m_enc[r * NH + 1]);
    float m2 = decf(m_enc[r * NH + 2]);
    float m3 = decf(m_enc[r * NH + 3]);
    float4 p;
    p.x = expf(ev.x - m0);
    p.y = expf(ev.y - m1);
    p.z = expf(ev.z - m2);
    p.w = expf(ev.w - m3);
    *(float4*)&ep[ed * NH] = p;
    unsafeAtomicAdd(&s[r * NH + 0], p.x);
    unsafeAtomicAdd(&s[r * NH + 1], p.y);
    unsafeAtomicAdd(&s[r * NH + 2], p.z);
    unsafeAtomicAdd(&s[r * NH + 3], p.w);
}

// Aggregation: one wave per edge, out[row] += att * h[col].
__global__ __launch_bounds__(256) void k_agg(
    const int* __restrict__ row, const int* __restrict__ col,
    const float* __restrict__ p, const float* __restrict__ s,
    const float* __restrict__ h, float* __restrict__ out) {
    const int wid = (int)((blockIdx.x * 256 + threadIdx.x) >> 6);  // edge id
    const int lane = threadIdx.x & 63;
    if (wid >= NE) return;
    const int r = row[wid], c = col[wid];
    float4 pv = *(const float4*)&p[wid * NH];
    float4 sv = *(const float4*)&s[r * NH];
    float att[4] = {pv.x / sv.x, pv.y / sv.y, pv.z / sv.z, pv.w / sv.w};
    float2 hv = *(const float2*)&h[c * OC + lane * 2];
    float a = att[lane >> 4];
    unsafeAtomicAdd(&out[r * OC + lane * 2 + 0], a * hv.x);
    unsafeAtomicAdd(&out[r * OC + lane * 2 + 1], a * hv.y);
}

extern "C" void kernel_launch(void* const* d_in, const int* in_sizes, int n_in,
                              void* d_out, int out_size, void* d_ws, size_t ws_size,
                              hipStream_t stream) {
    const float* x    = (const float*)d_in[0];
    const int*   ei   = (const int*)d_in[1];    // [2, NE]
    const float* W    = (const float*)d_in[2];
    const float* a_l  = (const float*)d_in[3];
    const float* a_r  = (const float*)d_in[4];
    float* out = (float*)d_out;

    const int* row = ei;         // destination
    const int* col = ei + NE;    // source

    float* ws = (float*)d_ws;
    float*    h     = ws;                       // NN*OC
    float*    al    = h + (size_t)NN * OC;      // NN*NH
    float*    ar    = al + (size_t)NN * NH;     // NN*NH
    unsigned* m_enc = (unsigned*)(ar + (size_t)NN * NH); // NN*NH
    float*    s     = (float*)m_enc + (size_t)NN * NH;   // NN*NH
    float*    ep    = s + (size_t)NN * NH;      // NE*NH (e then p in place)

    hipMemsetAsync(d_out, 0, (size_t)NN * OC * sizeof(float), stream);
    hipMemsetAsync(m_enc, 0, (size_t)NN * NH * sizeof(unsigned), stream);
    hipMemsetAsync(s, 0, (size_t)NN * NH * sizeof(float), stream);

    k_gemm<<<NN / 32, 256, 0, stream>>>(x, W, a_l, a_r, h, al, ar);
    k_edge_max<<<(NE + 255) / 256, 256, 0, stream>>>(row, col, al, ar, ep, m_enc);
    k_exp_sum<<<(NE + 255) / 256, 256, 0, stream>>>(row, m_enc, ep, s);
    k_agg<<<(NE * 64 + 255) / 256, 256, 0, stream>>>(row, col, ep, s, h, out);
}

// Round 2
// 500.289 us; speedup vs baseline: 4.0609x; 4.0609x over previous
//
#include <hip/hip_runtime.h>
#include <hip/hip_bf16.h>

#define NN 100000
#define NE 1600000
#define INF_ 128
#define OC 128   // NHEAD*OUT_F
#define NH 4
#define ALPHA 0.2f
#define NBLK ((NN + 1023) / 1024)   // 98 scan blocks

__device__ __forceinline__ float lrelu(float x) {
    return x > 0.0f ? x : ALPHA * x;
}

// GEMM h = x @ W, fused per-node attention halves al/ar.
__global__ __launch_bounds__(256) void k_gemm(
    const float* __restrict__ x, const float* __restrict__ W,
    const float* __restrict__ a_l, const float* __restrict__ a_r,
    float* __restrict__ h, float* __restrict__ al, float* __restrict__ ar) {
    __shared__ float Wl[INF_ * OC];      // 64 KB
    __shared__ float xs[32][INF_];       // 16 KB
    const int tid = threadIdx.x;
    for (int i = tid * 4; i < INF_ * OC; i += 256 * 4)
        *(float4*)&Wl[i] = *(const float4*)&W[i];
    const int rowBase = blockIdx.x * 32;
    for (int i = tid * 4; i < 32 * INF_; i += 256 * 4) {
        int r = i >> 7, k = i & 127;
        *(float4*)&xs[r][k] = *(const float4*)&x[(rowBase + r) * INF_ + k];
    }
    __syncthreads();

    const int col = tid & 127;
    const int grp = tid >> 7;
    const int hd  = col >> 5;
    const float alc = a_l[col], arc = a_r[col];

    for (int pass = 0; pass < 4; ++pass) {
        const int r0 = grp * 16 + pass * 4;
        float acc0 = 0.f, acc1 = 0.f, acc2 = 0.f, acc3 = 0.f;
#pragma unroll 8
        for (int k = 0; k < INF_; ++k) {
            float w = Wl[k * OC + col];
            acc0 += xs[r0 + 0][k] * w;
            acc1 += xs[r0 + 1][k] * w;
            acc2 += xs[r0 + 2][k] * w;
            acc3 += xs[r0 + 3][k] * w;
        }
        float accs[4] = {acc0, acc1, acc2, acc3};
#pragma unroll
        for (int i = 0; i < 4; ++i) {
            const int row = rowBase + r0 + i;
            float v = accs[i];
            h[row * OC + col] = v;
            float pl = v * alc;
            float pr = v * arc;
#pragma unroll
            for (int m = 1; m <= 16; m <<= 1) {
                pl += __shfl_xor(pl, m);
                pr += __shfl_xor(pr, m);
            }
            if ((col & 31) == 0) {
                al[row * NH + hd] = pl;
                ar[row * NH + hd] = pr;
            }
        }
    }
}

// Histogram of destination degree.
__global__ __launch_bounds__(256) void k_hist(
    const int* __restrict__ row, int* __restrict__ deg) {
    const int ed = blockIdx.x * 256 + threadIdx.x;
    if (ed >= NE) return;
    atomicAdd(&deg[row[ed]], 1);
}

// Scan phase A: per-block (1024 elems) sums.
__global__ __launch_bounds__(256) void k_bsum(
    const int* __restrict__ deg, int* __restrict__ bsum) {
    __shared__ int red[256];
    const int b = blockIdx.x, t = threadIdx.x;
    const int base = b * 1024 + t * 4;
    int s = 0;
#pragma unroll
    for (int i = 0; i < 4; ++i) {
        int idx = base + i;
        if (idx < NN) s += deg[idx];
    }
    red[t] = s;
    __syncthreads();
    for (int o = 128; o > 0; o >>= 1) {
        if (t < o) red[t] += red[t + o];
        __syncthreads();
    }
    if (t == 0) bsum[b] = red[0];
}

// Scan phase B: exclusive scan of 98 block sums (trivial serial).
__global__ void k_bscan(const int* __restrict__ bsum, int* __restrict__ bbase,
                        int* __restrict__ offs) {
    if (threadIdx.x == 0) {
        int acc = 0;
        for (int i = 0; i < NBLK; ++i) { bbase[i] = acc; acc += bsum[i]; }
        offs[NN] = NE;
    }
}

// Scan phase C: final exclusive offsets.
__global__ __launch_bounds__(256) void k_offs(
    const int* __restrict__ deg, const int* __restrict__ bbase,
    int* __restrict__ offs) {
    __shared__ int ts[256];
    const int b = blockIdx.x, t = threadIdx.x;
    const int base = b * 1024 + t * 4;
    int v[4];
    int s = 0;
#pragma unroll
    for (int i = 0; i < 4; ++i) {
        int idx = base + i;
        v[i] = (idx < NN) ? deg[idx] : 0;
        s += v[i];
    }
    ts[t] = s;
    __syncthreads();
    for (int o = 1; o < 256; o <<= 1) {
        int add = (t >= o) ? ts[t - o] : 0;
        __syncthreads();
        ts[t] += add;
        __syncthreads();
    }
    int ex = ts[t] - s + bbase[b];   // exclusive prefix for this thread
#pragma unroll
    for (int i = 0; i < 4; ++i) {
        int idx = base + i;
        if (idx < NN) offs[idx] = ex;
        ex += v[i];
    }
}

// Scatter: recompute raw scores, write (col, e4) to CSR slot.
__global__ __launch_bounds__(256) void k_scatter(
    const int* __restrict__ row, const int* __restrict__ col,
    const float* __restrict__ al, const float* __restrict__ ar,
    const int* __restrict__ offs, int* __restrict__ cursor,
    int* __restrict__ cols_s, float* __restrict__ es) {
    const int ed = blockIdx.x * 256 + threadIdx.x;
    if (ed >= NE) return;
    const int r = row[ed], c = col[ed];
    float4 a = *(const float4*)&al[r * NH];
    float4 b = *(const float4*)&ar[c * NH];
    float4 ev;
    ev.x = lrelu(a.x + b.x);
    ev.y = lrelu(a.y + b.y);
    ev.z = lrelu(a.z + b.z);
    ev.w = lrelu(a.w + b.w);
    const int pos = offs[r] + atomicAdd(&cursor[r], 1);
    cols_s[pos] = c;
    *(float4*)&es[pos * NH] = ev;
}

// Per-(node, head) softmax over the contiguous segment: es <- exp(e-m), s <- sum.
__global__ __launch_bounds__(256) void k_softmax(
    const int* __restrict__ offs, float* __restrict__ es, float* __restrict__ s) {
    const int t = blockIdx.x * 256 + threadIdx.x;
    if (t >= NN * NH) return;
    const int n = t >> 2, hd = t & 3;
    const int start = offs[n], end = offs[n + 1];
    if (start == end) { s[t] = 0.f; return; }
    float m = -1e30f;
    for (int k = start; k < end; ++k) m = fmaxf(m, es[k * NH + hd]);
    float ssum = 0.f;
    for (int k = start; k < end; ++k) {
        float p = expf(es[k * NH + hd] - m);
        es[k * NH + hd] = p;
        ssum += p;
    }
    s[t] = ssum;
}

// CSR aggregation: one wave per destination node, register accumulation.
__global__ __launch_bounds__(256) void k_agg(
    const int* __restrict__ offs, const int* __restrict__ cols_s,
    const float* __restrict__ es, const float* __restrict__ s,
    const float* __restrict__ h, float* __restrict__ out) {
    const int node = blockIdx.x * 4 + (threadIdx.x >> 6);
    const int lane = threadIdx.x & 63;
    if (node >= NN) return;
    const int start = offs[node], end = offs[node + 1];
    const int hd = lane >> 4;
    const float sv = s[node * NH + hd];
    const float inv = (sv != 0.f) ? 1.0f / sv : 0.f;
    float accx = 0.f, accy = 0.f;
    for (int k = start; k < end; ++k) {
        const int c = cols_s[k];
        const float p = es[k * NH + hd];
        const float2 hv = *(const float2*)&h[c * OC + lane * 2];
        const float a = p * inv;
        accx += a * hv.x;
        accy += a * hv.y;
    }
    float2 o;
    o.x = accx; o.y = accy;
    *(float2*)&out[node * OC + lane * 2] = o;
}

extern "C" void kernel_launch(void* const* d_in, const int* in_sizes, int n_in,
                              void* d_out, int out_size, void* d_ws, size_t ws_size,
                              hipStream_t stream) {
    const float* x    = (const float*)d_in[0];
    const int*   ei   = (const int*)d_in[1];    // [2, NE]
    const float* W    = (const float*)d_in[2];
    const float* a_l  = (const float*)d_in[3];
    const float* a_r  = (const float*)d_in[4];
    float* out = (float*)d_out;

    const int* row = ei;         // destination
    const int* col = ei + NE;    // source

    char* ws = (char*)d_ws;
    float* h      = (float*)ws;                 ws += (size_t)NN * OC * 4;   // 51.2 MB
    float* es     = (float*)ws;                 ws += (size_t)NE * NH * 4;   // 25.6 MB
    float* al     = (float*)ws;                 ws += (size_t)NN * NH * 4;
    float* ar     = (float*)ws;                 ws += (size_t)NN * NH * 4;
    float* s      = (float*)ws;                 ws += (size_t)NN * NH * 4;
    int*   cols_s = (int*)ws;                   ws += (size_t)NE * 4;        // 6.4 MB
    int*   deg    = (int*)ws;                   ws += (size_t)NN * 4;
    int*   cursor = (int*)ws;                   ws += (size_t)NN * 4;
    int*   offs   = (int*)ws;                   ws += (size_t)(NN + 1) * 4;
    int*   bsum   = (int*)ws;                   ws += (size_t)NBLK * 4;
    int*   bbase  = (int*)ws;

    hipMemsetAsync(deg, 0, (size_t)NN * 4, stream);
    hipMemsetAsync(cursor, 0, (size_t)NN * 4, stream);

    k_gemm<<<NN / 32, 256, 0, stream>>>(x, W, a_l, a_r, h, al, ar);
    k_hist<<<(NE + 255) / 256, 256, 0, stream>>>(row, deg);
    k_bsum<<<NBLK, 256, 0, stream>>>(deg, bsum);
    k_bscan<<<1, 64, 0, stream>>>(bsum, bbase, offs);
    k_offs<<<NBLK, 256, 0, stream>>>(deg, bbase, offs);
    k_scatter<<<(NE + 255) / 256, 256, 0, stream>>>(row, col, al, ar, offs, cursor, cols_s, es);
    k_softmax<<<(NN * NH + 255) / 256, 256, 0, stream>>>(offs, es, s);
    k_agg<<<(NN + 3) / 4, 256, 0, stream>>>(offs, cols_s, es, s, h, out);
}

// Round 3
// 404.260 us; speedup vs baseline: 5.0255x; 1.2375x over previous
//
#include <hip/hip_runtime.h>
#include <hip/hip_bf16.h>

#define NN 100000
#define NE 1600000
#define INF_ 128
#define OC 128   // NHEAD*OUT_F
#define NH 4
#define ALPHA 0.2f
#define NBLK ((NN + 1023) / 1024)   // 98 scan blocks

__device__ __forceinline__ float lrelu(float x) {
    return x > 0.0f ? x : ALPHA * x;
}

// GEMM h = x @ W (bf16 output), fused per-node attention halves al/ar (fp32).
__global__ __launch_bounds__(256) void k_gemm(
    const float* __restrict__ x, const float* __restrict__ W,
    const float* __restrict__ a_l, const float* __restrict__ a_r,
    __hip_bfloat16* __restrict__ h, float* __restrict__ al, float* __restrict__ ar) {
    __shared__ float Wl[INF_ * OC];      // 64 KB
    __shared__ float xs[32][INF_];       // 16 KB
    const int tid = threadIdx.x;
    for (int i = tid * 4; i < INF_ * OC; i += 256 * 4)
        *(float4*)&Wl[i] = *(const float4*)&W[i];
    const int rowBase = blockIdx.x * 32;
    for (int i = tid * 4; i < 32 * INF_; i += 256 * 4) {
        int r = i >> 7, k = i & 127;
        *(float4*)&xs[r][k] = *(const float4*)&x[(rowBase + r) * INF_ + k];
    }
    __syncthreads();

    const int col = tid & 127;
    const int grp = tid >> 7;
    const int hd  = col >> 5;
    const float alc = a_l[col], arc = a_r[col];

    for (int pass = 0; pass < 4; ++pass) {
        const int r0 = grp * 16 + pass * 4;
        float acc0 = 0.f, acc1 = 0.f, acc2 = 0.f, acc3 = 0.f;
#pragma unroll 8
        for (int k = 0; k < INF_; ++k) {
            float w = Wl[k * OC + col];
            acc0 += xs[r0 + 0][k] * w;
            acc1 += xs[r0 + 1][k] * w;
            acc2 += xs[r0 + 2][k] * w;
            acc3 += xs[r0 + 3][k] * w;
        }
        float accs[4] = {acc0, acc1, acc2, acc3};
#pragma unroll
        for (int i = 0; i < 4; ++i) {
            const int row = rowBase + r0 + i;
            float v = accs[i];
            h[(size_t)row * OC + col] = __float2bfloat16(v);
            float pl = v * alc;
            float pr = v * arc;
#pragma unroll
            for (int m = 1; m <= 16; m <<= 1) {
                pl += __shfl_xor(pl, m);
                pr += __shfl_xor(pr, m);
            }
            if ((col & 31) == 0) {
                al[row * NH + hd] = pl;
                ar[row * NH + hd] = pr;
            }
        }
    }
}

// Histogram of destination degree.
__global__ __launch_bounds__(256) void k_hist(
    const int* __restrict__ row, int* __restrict__ deg) {
    const int ed = blockIdx.x * 256 + threadIdx.x;
    if (ed >= NE) return;
    atomicAdd(&deg[row[ed]], 1);
}

// Scan phase A: per-block (1024 elems) sums.
__global__ __launch_bounds__(256) void k_bsum(
    const int* __restrict__ deg, int* __restrict__ bsum) {
    __shared__ int red[256];
    const int b = blockIdx.x, t = threadIdx.x;
    const int base = b * 1024 + t * 4;
    int s = 0;
#pragma unroll
    for (int i = 0; i < 4; ++i) {
        int idx = base + i;
        if (idx < NN) s += deg[idx];
    }
    red[t] = s;
    __syncthreads();
    for (int o = 128; o > 0; o >>= 1) {
        if (t < o) red[t] += red[t + o];
        __syncthreads();
    }
    if (t == 0) bsum[b] = red[0];
}

// Scan phase B: exclusive scan of block sums.
__global__ void k_bscan(const int* __restrict__ bsum, int* __restrict__ bbase,
                        int* __restrict__ offs) {
    if (threadIdx.x == 0) {
        int acc = 0;
        for (int i = 0; i < NBLK; ++i) { bbase[i] = acc; acc += bsum[i]; }
        offs[NN] = NE;
    }
}

// Scan phase C: final exclusive offsets.
__global__ __launch_bounds__(256) void k_offs(
    const int* __restrict__ deg, const int* __restrict__ bbase,
    int* __restrict__ offs) {
    __shared__ int ts[256];
    const int b = blockIdx.x, t = threadIdx.x;
    const int base = b * 1024 + t * 4;
    int v[4];
    int s = 0;
#pragma unroll
    for (int i = 0; i < 4; ++i) {
        int idx = base + i;
        v[i] = (idx < NN) ? deg[idx] : 0;
        s += v[i];
    }
    ts[t] = s;
    __syncthreads();
    for (int o = 1; o < 256; o <<= 1) {
        int add = (t >= o) ? ts[t - o] : 0;
        __syncthreads();
        ts[t] += add;
        __syncthreads();
    }
    int ex = ts[t] - s + bbase[b];
#pragma unroll
    for (int i = 0; i < 4; ++i) {
        int idx = base + i;
        if (idx < NN) offs[idx] = ex;
        ex += v[i];
    }
}

// Scatter: recompute raw scores, write (col, e4) to CSR slot.
__global__ __launch_bounds__(256) void k_scatter(
    const int* __restrict__ row, const int* __restrict__ col,
    const float* __restrict__ al, const float* __restrict__ ar,
    const int* __restrict__ offs, int* __restrict__ cursor,
    int* __restrict__ cols_s, float* __restrict__ es) {
    const int ed = blockIdx.x * 256 + threadIdx.x;
    if (ed >= NE) return;
    const int r = row[ed], c = col[ed];
    float4 a = *(const float4*)&al[r * NH];
    float4 b = *(const float4*)&ar[c * NH];
    float4 ev;
    ev.x = lrelu(a.x + b.x);
    ev.y = lrelu(a.y + b.y);
    ev.z = lrelu(a.z + b.z);
    ev.w = lrelu(a.w + b.w);
    const int pos = offs[r] + atomicAdd(&cursor[r], 1);
    cols_s[pos] = c;
    *(float4*)&es[pos * NH] = ev;
}

// Fused softmax + CSR aggregation: one wave per destination node.
__global__ __launch_bounds__(256) void k_agg(
    const int* __restrict__ offs, const int* __restrict__ cols_s,
    const float* __restrict__ es, const __hip_bfloat16* __restrict__ hb,
    float* __restrict__ out) {
    const int node = blockIdx.x * 4 + (threadIdx.x >> 6);
    const int lane = threadIdx.x & 63;
    if (node >= NN) return;
    const int start = offs[node], end = offs[node + 1];
    if (start == end) {
        *(float2*)&out[(size_t)node * OC + lane * 2] = make_float2(0.f, 0.f);
        return;
    }
    // Phase 1: per-head max + sum over the segment (coalesced sweeps).
    const int sh = lane & 3;   // head this lane reduces
    const int se = lane >> 2;  // edge slot within 16-edge sweep
    float m = -1e30f;
    for (int base = start; base < end; base += 16) {
        const int k = base + se;
        if (k < end) m = fmaxf(m, es[k * NH + sh]);
    }
#pragma unroll
    for (int msk = 4; msk <= 32; msk <<= 1) m = fmaxf(m, __shfl_xor(m, msk));
    float ssum = 0.f;
    for (int base = start; base < end; base += 16) {
        const int k = base + se;
        if (k < end) ssum += expf(es[k * NH + sh] - m);
    }
#pragma unroll
    for (int msk = 4; msk <= 32; msk <<= 1) ssum += __shfl_xor(ssum, msk);

    const int hd = lane >> 4;              // head this lane accumulates
    const float mh  = __shfl(m, hd);       // lanes 0..3 hold heads 0..3
    const float inv = 1.0f / __shfl(ssum, hd);

    // Phase 2: gather-accumulate, 4 edges in flight.
    const size_t loff = (size_t)(lane * 2);
    float accx = 0.f, accy = 0.f;
    int k = start;
    for (; k + 4 <= end; k += 4) {
        const int c0 = cols_s[k + 0], c1 = cols_s[k + 1];
        const int c2 = cols_s[k + 2], c3 = cols_s[k + 3];
        const float e0 = es[(k + 0) * NH + hd], e1 = es[(k + 1) * NH + hd];
        const float e2 = es[(k + 2) * NH + hd], e3 = es[(k + 3) * NH + hd];
        const unsigned v0 = *(const unsigned*)&hb[(size_t)c0 * OC + loff];
        const unsigned v1 = *(const unsigned*)&hb[(size_t)c1 * OC + loff];
        const unsigned v2 = *(const unsigned*)&hb[(size_t)c2 * OC + loff];
        const unsigned v3 = *(const unsigned*)&hb[(size_t)c3 * OC + loff];
        const float p0 = expf(e0 - mh) * inv;
        const float p1 = expf(e1 - mh) * inv;
        const float p2 = expf(e2 - mh) * inv;
        const float p3 = expf(e3 - mh) * inv;
        accx += p0 * __uint_as_float(v0 << 16);
        accy += p0 * __uint_as_float(v0 & 0xffff0000u);
        accx += p1 * __uint_as_float(v1 << 16);
        accy += p1 * __uint_as_float(v1 & 0xffff0000u);
        accx += p2 * __uint_as_float(v2 << 16);
        accy += p2 * __uint_as_float(v2 & 0xffff0000u);
        accx += p3 * __uint_as_float(v3 << 16);
        accy += p3 * __uint_as_float(v3 & 0xffff0000u);
    }
    for (; k < end; ++k) {
        const int c = cols_s[k];
        const float p = expf(es[k * NH + hd] - mh) * inv;
        const unsigned v = *(const unsigned*)&hb[(size_t)c * OC + loff];
        accx += p * __uint_as_float(v << 16);
        accy += p * __uint_as_float(v & 0xffff0000u);
    }
    float2 o; o.x = accx; o.y = accy;
    *(float2*)&out[(size_t)node * OC + loff] = o;
}

extern "C" void kernel_launch(void* const* d_in, const int* in_sizes, int n_in,
                              void* d_out, int out_size, void* d_ws, size_t ws_size,
                              hipStream_t stream) {
    const float* x    = (const float*)d_in[0];
    const int*   ei   = (const int*)d_in[1];    // [2, NE]
    const float* W    = (const float*)d_in[2];
    const float* a_l  = (const float*)d_in[3];
    const float* a_r  = (const float*)d_in[4];
    float* out = (float*)d_out;

    const int* row = ei;         // destination
    const int* col = ei + NE;    // source

    char* ws = (char*)d_ws;
    __hip_bfloat16* hb = (__hip_bfloat16*)ws;   ws += (size_t)NN * OC * 2;   // 25.6 MB
    float* es     = (float*)ws;                 ws += (size_t)NE * NH * 4;   // 25.6 MB
    float* al     = (float*)ws;                 ws += (size_t)NN * NH * 4;
    float* ar     = (float*)ws;                 ws += (size_t)NN * NH * 4;
    int*   cols_s = (int*)ws;                   ws += (size_t)NE * 4;        // 6.4 MB
    int*   deg    = (int*)ws;                   ws += (size_t)NN * 4;
    int*   cursor = (int*)ws;                   ws += (size_t)NN * 4;
    int*   offs   = (int*)ws;                   ws += (size_t)(NN + 1) * 4;
    int*   bsum   = (int*)ws;                   ws += (size_t)NBLK * 4;
    int*   bbase  = (int*)ws;

    hipMemsetAsync(deg, 0, (size_t)NN * 4, stream);
    hipMemsetAsync(cursor, 0, (size_t)NN * 4, stream);

    k_gemm<<<NN / 32, 256, 0, stream>>>(x, W, a_l, a_r, hb, al, ar);
    k_hist<<<(NE + 255) / 256, 256, 0, stream>>>(row, deg);
    k_bsum<<<NBLK, 256, 0, stream>>>(deg, bsum);
    k_bscan<<<1, 64, 0, stream>>>(bsum, bbase, offs);
    k_offs<<<NBLK, 256, 0, stream>>>(deg, bbase, offs);
    k_scatter<<<(NE + 255) / 256, 256, 0, stream>>>(row, col, al, ar, offs, cursor, cols_s, es);
    k_agg<<<(NN + 3) / 4, 256, 0, stream>>>(offs, cols_s, es, hb, out);
}

// Round 4
// 305.156 us; speedup vs baseline: 6.6576x; 1.3248x over previous
//
#include <hip/hip_runtime.h>
#include <hip/hip_bf16.h>
#include <string.h>

#define NN 100000
#define NE 1600000
#define INF_ 128
#define OC 128   // NHEAD*OUT_F
#define NH 4
#define ALPHA 0.2f
#define NBLK ((NN + 1023) / 1024)   // 98 scan blocks
#define LDA 272                      // LDS row stride in bytes (256 + 16 pad)

typedef __bf16 bf16x8 __attribute__((ext_vector_type(8)));
typedef float f32x4 __attribute__((ext_vector_type(4)));

__device__ __forceinline__ float lrelu(float x) {
    return x > 0.0f ? x : ALPHA * x;
}
__device__ __forceinline__ unsigned short f2bf(float f) {
    __hip_bfloat16 b = __float2bfloat16(f);
    unsigned short u; memcpy(&u, &b, 2); return u;
}

// MFMA GEMM: h = x @ W, bf16 inputs (converted on the fly), fp32 accum, bf16 out.
// Block: 256 threads / 4 waves; tile 64 rows x 128 cols; K=128.
__global__ __launch_bounds__(256) void k_gemm(
    const float* __restrict__ x, const float* __restrict__ W,
    __hip_bfloat16* __restrict__ hb) {
    __shared__ __align__(16) char sA[64 * LDA];    // x tile, bf16 [64][128]
    __shared__ __align__(16) char sB[128 * LDA];   // Wt, bf16 [col][k]
    const int tid = threadIdx.x;
    const int rowBase = blockIdx.x * 64;

    // Stage x tile: 2048 float4 segments, convert to bf16.
    {
        union { uint2 d; unsigned short u[4]; } pk;
        for (int j = 0; j < 8; ++j) {
            const int i4 = tid + j * 256;          // < 2048
            const int r = i4 >> 5, c4 = i4 & 31;   // row, float4-index
            const int g = rowBase + r;
            float4 v = make_float4(0.f, 0.f, 0.f, 0.f);
            if (g < NN) v = *(const float4*)&x[(size_t)g * INF_ + c4 * 4];
            pk.u[0] = f2bf(v.x); pk.u[1] = f2bf(v.y);
            pk.u[2] = f2bf(v.z); pk.u[3] = f2bf(v.w);
            *(uint2*)(sA + r * LDA + c4 * 8) = pk.d;
        }
    }
    // Stage W transposed: thread t -> col c = t&127, k-half kh = t>>7.
    {
        const int c = tid & 127, kh = tid >> 7;
        union { uint4 q; unsigned short u[8]; } pk;
        for (int kb = 0; kb < 8; ++kb) {
            const int k0 = kh * 64 + kb * 8;
#pragma unroll
            for (int j = 0; j < 8; ++j)
                pk.u[j] = f2bf(W[(size_t)(k0 + j) * OC + c]);
            *(uint4*)(sB + c * LDA + k0 * 2) = pk.q;
        }
    }
    __syncthreads();

    const int lane = tid & 63;
    const int w = tid >> 6;
    const int arow = w * 16 + (lane & 15);
    const int koff = (lane >> 4) * 16;       // byte offset of lane's k-group

    f32x4 acc[8];
#pragma unroll
    for (int n = 0; n < 8; ++n) acc[n] = (f32x4){0.f, 0.f, 0.f, 0.f};

#pragma unroll
    for (int kk = 0; kk < 4; ++kk) {
        const bf16x8 a = *(const bf16x8*)(sA + arow * LDA + kk * 64 + koff);
#pragma unroll
        for (int n = 0; n < 8; ++n) {
            const int brow = n * 16 + (lane & 15);
            const bf16x8 b = *(const bf16x8*)(sB + brow * LDA + kk * 64 + koff);
            acc[n] = __builtin_amdgcn_mfma_f32_16x16x32_bf16(a, b, acc[n], 0, 0, 0);
        }
    }

    // C store: col = n*16 + (lane&15), row = (lane>>4)*4 + r.
    const int rbase = rowBase + w * 16 + (lane >> 4) * 4;
#pragma unroll
    for (int n = 0; n < 8; ++n) {
        const int col = n * 16 + (lane & 15);
#pragma unroll
        for (int r = 0; r < 4; ++r) {
            const int row = rbase + r;
            if (row < NN) hb[(size_t)row * OC + col] = __float2bfloat16(acc[n][r]);
        }
    }
}

// Per-(node, head) attention halves from bf16 h.
__global__ __launch_bounds__(256) void k_att(
    const __hip_bfloat16* __restrict__ hb,
    const float* __restrict__ a_l, const float* __restrict__ a_r,
    float* __restrict__ al, float* __restrict__ ar) {
    const int t = blockIdx.x * 256 + threadIdx.x;
    if (t >= NN * NH) return;
    const int n = t >> 2, hd = t & 3;
    const uint4* hp = (const uint4*)((const char*)hb + (size_t)n * 256 + hd * 64);
    const float* alc = a_l + hd * 32;
    const float* arc = a_r + hd * 32;
    float sl = 0.f, sr = 0.f;
#pragma unroll
    for (int q = 0; q < 4; ++q) {
        const uint4 v = hp[q];
        const unsigned uu[4] = {v.x, v.y, v.z, v.w};
#pragma unroll
        for (int i = 0; i < 4; ++i) {
            const int k = q * 8 + i * 2;
            const float lo = __uint_as_float(uu[i] << 16);
            const float hi = __uint_as_float(uu[i] & 0xffff0000u);
            sl += lo * alc[k] + hi * alc[k + 1];
            sr += lo * arc[k] + hi * arc[k + 1];
        }
    }
    al[t] = sl;
    ar[t] = sr;
}

// Histogram of destination degree.
__global__ __launch_bounds__(256) void k_hist(
    const int* __restrict__ row, int* __restrict__ deg) {
    const int ed = blockIdx.x * 256 + threadIdx.x;
    if (ed >= NE) return;
    atomicAdd(&deg[row[ed]], 1);
}

// Scan phase A: per-block (1024 elems) sums.
__global__ __launch_bounds__(256) void k_bsum(
    const int* __restrict__ deg, int* __restrict__ bsum) {
    __shared__ int red[256];
    const int b = blockIdx.x, t = threadIdx.x;
    const int base = b * 1024 + t * 4;
    int s = 0;
#pragma unroll
    for (int i = 0; i < 4; ++i) {
        int idx = base + i;
        if (idx < NN) s += deg[idx];
    }
    red[t] = s;
    __syncthreads();
    for (int o = 128; o > 0; o >>= 1) {
        if (t < o) red[t] += red[t + o];
        __syncthreads();
    }
    if (t == 0) bsum[b] = red[0];
}

// Scan phase B: exclusive scan of block sums.
__global__ void k_bscan(const int* __restrict__ bsum, int* __restrict__ bbase,
                        int* __restrict__ offs) {
    if (threadIdx.x == 0) {
        int acc = 0;
        for (int i = 0; i < NBLK; ++i) { bbase[i] = acc; acc += bsum[i]; }
        offs[NN] = NE;
    }
}

// Scan phase C: final exclusive offsets.
__global__ __launch_bounds__(256) void k_offs(
    const int* __restrict__ deg, const int* __restrict__ bbase,
    int* __restrict__ offs) {
    __shared__ int ts[256];
    const int b = blockIdx.x, t = threadIdx.x;
    const int base = b * 1024 + t * 4;
    int v[4];
    int s = 0;
#pragma unroll
    for (int i = 0; i < 4; ++i) {
        int idx = base + i;
        v[i] = (idx < NN) ? deg[idx] : 0;
        s += v[i];
    }
    ts[t] = s;
    __syncthreads();
    for (int o = 1; o < 256; o <<= 1) {
        int add = (t >= o) ? ts[t - o] : 0;
        __syncthreads();
        ts[t] += add;
        __syncthreads();
    }
    int ex = ts[t] - s + bbase[b];
#pragma unroll
    for (int i = 0; i < 4; ++i) {
        int idx = base + i;
        if (idx < NN) offs[idx] = ex;
        ex += v[i];
    }
}

// Scatter: recompute raw scores, write (col, e4) to CSR slot.
__global__ __launch_bounds__(256) void k_scatter(
    const int* __restrict__ row, const int* __restrict__ col,
    const float* __restrict__ al, const float* __restrict__ ar,
    const int* __restrict__ offs, int* __restrict__ cursor,
    int* __restrict__ cols_s, float* __restrict__ es) {
    const int ed = blockIdx.x * 256 + threadIdx.x;
    if (ed >= NE) return;
    const int r = row[ed], c = col[ed];
    float4 a = *(const float4*)&al[r * NH];
    float4 b = *(const float4*)&ar[c * NH];
    float4 ev;
    ev.x = lrelu(a.x + b.x);
    ev.y = lrelu(a.y + b.y);
    ev.z = lrelu(a.z + b.z);
    ev.w = lrelu(a.w + b.w);
    const int pos = offs[r] + atomicAdd(&cursor[r], 1);
    cols_s[pos] = c;
    *(float4*)&es[pos * NH] = ev;
}

// Fused softmax + CSR aggregation: one wave per destination node.
__global__ __launch_bounds__(256) void k_agg(
    const int* __restrict__ offs, const int* __restrict__ cols_s,
    const float* __restrict__ es, const __hip_bfloat16* __restrict__ hb,
    float* __restrict__ out) {
    const int node = blockIdx.x * 4 + (threadIdx.x >> 6);
    const int lane = threadIdx.x & 63;
    if (node >= NN) return;
    const int start = offs[node], end = offs[node + 1];
    if (start == end) {
        *(float2*)&out[(size_t)node * OC + lane * 2] = make_float2(0.f, 0.f);
        return;
    }
    // Phase 1: per-head max + sum over the segment.
    const int sh = lane & 3;   // head this lane reduces
    const int se = lane >> 2;  // edge slot within 16-edge sweep
    float m = -1e30f;
    for (int base = start; base < end; base += 16) {
        const int k = base + se;
        if (k < end) m = fmaxf(m, es[k * NH + sh]);
    }
#pragma unroll
    for (int msk = 4; msk <= 32; msk <<= 1) m = fmaxf(m, __shfl_xor(m, msk));
    float ssum = 0.f;
    for (int base = start; base < end; base += 16) {
        const int k = base + se;
        if (k < end) ssum += expf(es[k * NH + sh] - m);
    }
#pragma unroll
    for (int msk = 4; msk <= 32; msk <<= 1) ssum += __shfl_xor(ssum, msk);

    const int hd = lane >> 4;
    const float mh  = __shfl(m, hd);
    const float inv = 1.0f / __shfl(ssum, hd);

    // Phase 2: gather-accumulate, 4 edges in flight.
    const size_t loff = (size_t)(lane * 2);
    float accx = 0.f, accy = 0.f;
    int k = start;
    for (; k + 4 <= end; k += 4) {
        const int c0 = cols_s[k + 0], c1 = cols_s[k + 1];
        const int c2 = cols_s[k + 2], c3 = cols_s[k + 3];
        const float e0 = es[(k + 0) * NH + hd], e1 = es[(k + 1) * NH + hd];
        const float e2 = es[(k + 2) * NH + hd], e3 = es[(k + 3) * NH + hd];
        const unsigned v0 = *(const unsigned*)&hb[(size_t)c0 * OC + loff];
        const unsigned v1 = *(const unsigned*)&hb[(size_t)c1 * OC + loff];
        const unsigned v2 = *(const unsigned*)&hb[(size_t)c2 * OC + loff];
        const unsigned v3 = *(const unsigned*)&hb[(size_t)c3 * OC + loff];
        const float p0 = expf(e0 - mh) * inv;
        const float p1 = expf(e1 - mh) * inv;
        const float p2 = expf(e2 - mh) * inv;
        const float p3 = expf(e3 - mh) * inv;
        accx += p0 * __uint_as_float(v0 << 16);
        accy += p0 * __uint_as_float(v0 & 0xffff0000u);
        accx += p1 * __uint_as_float(v1 << 16);
        accy += p1 * __uint_as_float(v1 & 0xffff0000u);
        accx += p2 * __uint_as_float(v2 << 16);
        accy += p2 * __uint_as_float(v2 & 0xffff0000u);
        accx += p3 * __uint_as_float(v3 << 16);
        accy += p3 * __uint_as_float(v3 & 0xffff0000u);
    }
    for (; k < end; ++k) {
        const int c = cols_s[k];
        const float p = expf(es[k * NH + hd] - mh) * inv;
        const unsigned v = *(const unsigned*)&hb[(size_t)c * OC + loff];
        accx += p * __uint_as_float(v << 16);
        accy += p * __uint_as_float(v & 0xffff0000u);
    }
    float2 o; o.x = accx; o.y = accy;
    *(float2*)&out[(size_t)node * OC + loff] = o;
}

extern "C" void kernel_launch(void* const* d_in, const int* in_sizes, int n_in,
                              void* d_out, int out_size, void* d_ws, size_t ws_size,
                              hipStream_t stream) {
    const float* x    = (const float*)d_in[0];
    const int*   ei   = (const int*)d_in[1];    // [2, NE]
    const float* W    = (const float*)d_in[2];
    const float* a_l  = (const float*)d_in[3];
    const float* a_r  = (const float*)d_in[4];
    float* out = (float*)d_out;

    const int* row = ei;         // destination
    const int* col = ei + NE;    // source

    char* ws = (char*)d_ws;
    __hip_bfloat16* hb = (__hip_bfloat16*)ws;   ws += (size_t)NN * OC * 2;   // 25.6 MB
    float* es     = (float*)ws;                 ws += (size_t)NE * NH * 4;   // 25.6 MB
    float* al     = (float*)ws;                 ws += (size_t)NN * NH * 4;
    float* ar     = (float*)ws;                 ws += (size_t)NN * NH * 4;
    int*   cols_s = (int*)ws;                   ws += (size_t)NE * 4;        // 6.4 MB
    int*   deg    = (int*)ws;                   ws += (size_t)NN * 4;
    int*   cursor = (int*)ws;                   ws += (size_t)NN * 4;
    int*   offs   = (int*)ws;                   ws += (size_t)(NN + 1) * 4;
    int*   bsum   = (int*)ws;                   ws += (size_t)NBLK * 4;
    int*   bbase  = (int*)ws;

    hipMemsetAsync(deg, 0, (size_t)NN * 4, stream);
    hipMemsetAsync(cursor, 0, (size_t)NN * 4, stream);

    k_gemm<<<(NN + 63) / 64, 256, 0, stream>>>(x, W, hb);
    k_att<<<(NN * NH + 255) / 256, 256, 0, stream>>>(hb, a_l, a_r, al, ar);
    k_hist<<<(NE + 255) / 256, 256, 0, stream>>>(row, deg);
    k_bsum<<<NBLK, 256, 0, stream>>>(deg, bsum);
    k_bscan<<<1, 64, 0, stream>>>(bsum, bbase, offs);
    k_offs<<<NBLK, 256, 0, stream>>>(deg, bbase, offs);
    k_scatter<<<(NE + 255) / 256, 256, 0, stream>>>(row, col, al, ar, offs, cursor, cols_s, es);
    k_agg<<<(NN + 3) / 4, 256, 0, stream>>>(offs, cols_s, es, hb, out);
}